// Round 9
// baseline (224.663 us; speedup 1.0000x reference)
//
#include <hip/hip_runtime.h>
#include <hip/hip_cooperative_groups.h>

namespace cg = cooperative_groups;

namespace {
constexpr int Bc  = 4;
constexpr int Lc  = 4096;
constexpr int Dc  = 2048;
constexpr int Gc  = 32;
constexpr int GSc = 64;
constexpr float EPSc = 1e-5f;
constexpr long long NY = (long long)Bc * Lc * Dc;   // 33,554,432
constexpr long long NM = (long long)Bc * Gc * Lc;   // 524,288
// coop geometry
constexpr int CTc = 512;                 // timesteps per chunk
constexpr int NCc = Lc / CTc;            // 8 chunks per bg
constexpr int JBc = NCc / 2;             // 4 blocks per bg (2 chunks each)
// fallback geometry (R5)
constexpr int CHUNKS = 8;
constexpr int CT2 = Lc / CHUNKS;         // 512
typedef float vfloat4 __attribute__((ext_vector_type(4)));
}

// ============================ COOP PATH =====================================
// Fused single-pass: grid = 512 blocks (2/CU capacity needed -> 2x margin),
// block (bg,j) owns chunks j and j+JBc. Per phase: read x slice, group means,
// in-block fp64 scan (2 elems/thread), publish chunk totals, grid.sync,
// gather carry (no polling), fp32 rcp/rsq finalize, normalize (x reload is
// L2/L3-hot), NT-store y. Two grid syncs, zero atomics.
__global__ __launch_bounds__(256, 4) void kCoop(
        const float* __restrict__ x,
        const int* __restrict__ prev_count,
        const float* __restrict__ prev_mean,
        const float* __restrict__ prev_var,
        const int* __restrict__ mask,
        const float* __restrict__ w,
        const float* __restrict__ bias,
        float* __restrict__ y,
        float* __restrict__ out_count,
        float* __restrict__ out_mean,
        float* __restrict__ out_var,
        double* __restrict__ part) {
    cg::grid_group grid = cg::this_grid();

    const int blk = blockIdx.x;
    const int bg = blk >> 2, j = blk & 3;
    const int b = bg >> 5, g = bg & (Gc - 1);
    const int tid = threadIdx.x;
    const int r16 = tid >> 4, col4 = tid & 15;

    __shared__ float  sm[CTc];
    __shared__ float  smean[CTc], srstd[CTc];
    __shared__ double s1[256], s2[256];
    __shared__ int    scnt[256];
    __shared__ double cLDS[3];

    const double c0    = (double)prev_count[b];
    const double mean0 = (double)prev_mean[bg];
    const double M2_0  = (double)prev_var[bg] * fmax(c0, 1.0);
    const float c0f = (float)c0, mean0f = (float)mean0, M2_0f = (float)M2_0;

    const float4 wv  = *reinterpret_cast<const float4*>(w + g * GSc + col4 * 4);
    const float4 bvv = *reinterpret_cast<const float4*>(bias + g * GSc + col4 * 4);

    for (int phase = 0; phase < 2; ++phase) {
        const int c = j + phase * JBc;
        const int tbase = c * CTc;
        const long long xbase = ((long long)b * Lc + tbase) * Dc + (long long)g * GSc + col4 * 4;

        // ---- group means (16-lane segmented shfl), 32 iters of 16 rows ----
        for (int it = 0; it < CTc / 16; ++it) {
            const int r = it * 16 + r16;
            const float4 xv = *reinterpret_cast<const float4*>(x + xbase + (long long)r * Dc);
            float s = xv.x + xv.y + xv.z + xv.w;
            s += __shfl_xor(s, 1);
            s += __shfl_xor(s, 2);
            s += __shfl_xor(s, 4);
            s += __shfl_xor(s, 8);
            if (col4 == 0) sm[r] = s * (1.0f / GSc);
        }
        __syncthreads();

        // ---- masked fp64 scan, 2 timesteps per thread ----
        const int* mrow = mask + (long long)b * Lc + tbase;
        const float v0 = sm[2 * tid], v1 = sm[2 * tid + 1];
        const int q0 = mrow[2 * tid], q1 = mrow[2 * tid + 1];
        double ls1 = 0.0, ls2 = 0.0; int lc = 0;
        if (q0) { ls1 += v0; ls2 += (double)v0 * v0; ++lc; }
        if (q1) { ls1 += v1; ls2 += (double)v1 * v1; ++lc; }
        s1[tid] = ls1; s2[tid] = ls2; scnt[tid] = lc;
        __syncthreads();
        for (int off = 1; off < 256; off <<= 1) {
            double a1 = 0.0, a2 = 0.0; int ac = 0;
            if (tid >= off) { a1 = s1[tid - off]; a2 = s2[tid - off]; ac = scnt[tid - off]; }
            __syncthreads();
            s1[tid] += a1; s2[tid] += a2; scnt[tid] += ac;
            __syncthreads();
        }
        const double ex1 = s1[tid] - ls1, ex2 = s2[tid] - ls2;
        const int exc = scnt[tid] - lc;

        // ---- publish chunk totals (plain store; grid.sync orders) ----
        if (tid == 255) {
            double* p = part + (long long)(bg * NCc + c) * 3;
            p[0] = s1[255]; p[1] = s2[255]; p[2] = (double)scnt[255];
        }

        grid.sync();

        // ---- carry gather: lanes 0..c-1 (c <= 7), 8-lane xor reduce ----
        if (tid < 64) {
            double a1 = 0.0, a2 = 0.0, ac = 0.0;
            if (tid < c) {
                const double* p = part + (long long)(bg * NCc + tid) * 3;
                a1 = p[0]; a2 = p[1]; ac = p[2];
            }
            #pragma unroll
            for (int o = 1; o < 8; o <<= 1) {
                a1 += __shfl_xor(a1, o);
                a2 += __shfl_xor(a2, o);
                ac += __shfl_xor(ac, o);
            }
            if (tid == 0) { cLDS[0] = a1; cLDS[1] = a2; cLDS[2] = ac; }
        }
        __syncthreads();

        // ---- per-timestep finalize (fp32 rcp/rsq), 2 rows/thread ----
        double run1 = cLDS[0] + ex1, run2 = cLDS[1] + ex2, runc = cLDS[2] + (double)exc;
        #pragma unroll
        for (int e = 0; e < 2; ++e) {
            const float vv = e ? v1 : v0;
            const int qq = e ? q1 : q0;
            if (qq) { run1 += vv; run2 += (double)vv * vv; runc += 1.0; }
            float run1f = (float)run1, run2f = (float)run2, cv = (float)runc;
            float ctot = c0f + cv, csafe = fmaxf(ctot, 1.0f);
            float invcs = __builtin_amdgcn_rcpf(csafe);
            float meanT = fmaf(c0f, mean0f, run1f) * invcs;
            float M2 = M2_0f;
            if (runc > 0.0) {
                float invcv = __builtin_amdgcn_rcpf(cv);
                M2 += run2f - run1f * run1f * invcv;
                float dd = run1f * invcv - mean0f;
                M2 += dd * dd * c0f * cv * invcs;
            }
            float varT = M2 * invcs;
            smean[2 * tid + e] = meanT;
            srstd[2 * tid + e] = __builtin_amdgcn_rsqf(varT + EPSc);
        }

        // ---- final-state outputs (fp64) from last timestep ----
        if (c == NCc - 1 && tid == 255) {
            double ctot = c0 + runc, csafe = fmax(ctot, 1.0);
            double meanF = (c0 * mean0 + run1) / csafe;
            double M2 = M2_0;
            if (runc > 0.0) {
                M2 += run2 - run1 * run1 / runc;
                double dd = run1 / runc - mean0;
                M2 += dd * dd * c0 * runc / csafe;
            }
            if (g == 0) out_count[b] = (float)ctot;   // read back as float32
            out_mean[bg] = (float)meanF;
            out_var[bg]  = (float)(M2 / csafe);
        }
        __syncthreads();

        // ---- normalize: reload x (L2/L3-hot), NT-store y ----
        for (int it = 0; it < CTc / 16; ++it) {
            const int r = it * 16 + r16;
            const float mean = smean[r];
            const float rstd = srstd[r];
            const float4 xv = *reinterpret_cast<const float4*>(x + xbase + (long long)r * Dc);
            vfloat4 yv;
            yv.x = (xv.x - mean) * rstd * wv.x + bvv.x;
            yv.y = (xv.y - mean) * rstd * wv.y + bvv.y;
            yv.z = (xv.z - mean) * rstd * wv.z + bvv.z;
            yv.w = (xv.w - mean) * rstd * wv.w + bvv.w;
            __builtin_nontemporal_store(
                yv, reinterpret_cast<vfloat4*>(y + xbase + (long long)r * Dc));
        }
        __syncthreads();   // protect sm/smean/s1/s2 reuse next phase
    }
}

// ========================== FALLBACK PATH (R5) ==============================
__global__ __launch_bounds__(256) void kA(const float* __restrict__ x,
                                          const int* __restrict__ mask,
                                          float* __restrict__ gmeans,
                                          double* __restrict__ part) {
    int blk = blockIdx.x, chunk = blk & (CHUNKS - 1), bg = blk >> 3;
    int b = bg >> 5, g = bg & (Gc - 1);
    int tid = threadIdx.x, rowi = tid >> 4, col4 = tid & 15;
    const long long xbase = ((long long)b * Lc + (long long)chunk * CT2) * Dc + (long long)g * GSc;

    __shared__ float sm[CT2];
    for (int it = 0; it < CT2 / 16; ++it) {
        int r = it * 16 + rowi;
        const float4 xv = *reinterpret_cast<const float4*>(x + xbase + (long long)r * Dc + col4 * 4);
        float s = xv.x + xv.y + xv.z + xv.w;
        s += __shfl_xor(s, 1);
        s += __shfl_xor(s, 2);
        s += __shfl_xor(s, 4);
        s += __shfl_xor(s, 8);
        if (col4 == 0) sm[r] = s * (1.0f / GSc);
    }
    __syncthreads();

    if (tid < CT2 / 4) {
        float4 mv = *reinterpret_cast<float4*>(sm + tid * 4);
        *reinterpret_cast<float4*>(gmeans + (long long)bg * Lc + chunk * CT2 + tid * 4) = mv;
    }

    const int* mrow = mask + (long long)b * Lc + chunk * CT2;
    float v0 = sm[tid * 2], v1 = sm[tid * 2 + 1];
    int q0 = mrow[tid * 2], q1 = mrow[tid * 2 + 1];
    double ls1 = 0.0, ls2 = 0.0; int lc = 0;
    if (q0) { ls1 += v0; ls2 += (double)v0 * v0; ++lc; }
    if (q1) { ls1 += v1; ls2 += (double)v1 * v1; ++lc; }
    __shared__ double r1[256], r2[256];
    __shared__ int rc[256];
    r1[tid] = ls1; r2[tid] = ls2; rc[tid] = lc;
    __syncthreads();
    for (int off = 128; off > 0; off >>= 1) {
        if (tid < off) { r1[tid] += r1[tid + off]; r2[tid] += r2[tid + off]; rc[tid] += rc[tid + off]; }
        __syncthreads();
    }
    if (tid == 0) {
        double* p = part + ((long long)bg * CHUNKS + chunk) * 3;
        p[0] = r1[0]; p[1] = r2[0]; p[2] = (double)rc[0];
    }
}

__global__ __launch_bounds__(256) void kB(const float* __restrict__ x,
                                          const float* __restrict__ gmeans,
                                          const double* __restrict__ part,
                                          const int* __restrict__ prev_count,
                                          const float* __restrict__ prev_mean,
                                          const float* __restrict__ prev_var,
                                          const int* __restrict__ mask,
                                          const float* __restrict__ w,
                                          const float* __restrict__ bias,
                                          float* __restrict__ y,
                                          float* __restrict__ out_count,
                                          float* __restrict__ out_mean,
                                          float* __restrict__ out_var) {
    int blk = blockIdx.x, chunk = blk & (CHUNKS - 1), bg = blk >> 3;
    int b = bg >> 5, g = bg & (Gc - 1);
    int tid = threadIdx.x, rowi = tid >> 4, col4 = tid & 15;

    __shared__ float smean[CT2], srstd[CT2];
    __shared__ double s1[256], s2[256];
    __shared__ int sc[256];

    const float* mrow = gmeans + (long long)bg * Lc + chunk * CT2;
    const int* krow = mask + (long long)b * Lc + chunk * CT2;
    float v0 = mrow[tid * 2], v1 = mrow[tid * 2 + 1];
    int q0 = krow[tid * 2], q1 = krow[tid * 2 + 1];
    double ls1 = 0.0, ls2 = 0.0; int lc = 0;
    if (q0) { ls1 += v0; ls2 += (double)v0 * v0; ++lc; }
    if (q1) { ls1 += v1; ls2 += (double)v1 * v1; ++lc; }
    s1[tid] = ls1; s2[tid] = ls2; sc[tid] = lc;
    __syncthreads();
    for (int off = 1; off < 256; off <<= 1) {
        double a1 = 0.0, a2 = 0.0; int ac = 0;
        if (tid >= off) { a1 = s1[tid - off]; a2 = s2[tid - off]; ac = sc[tid - off]; }
        __syncthreads();
        s1[tid] += a1; s2[tid] += a2; sc[tid] += ac;
        __syncthreads();
    }
    double ex1 = s1[tid] - ls1, ex2 = s2[tid] - ls2;
    int exc = sc[tid] - lc;

    double c1 = 0.0, c2 = 0.0, ccnt = 0.0;
    const double* pb = part + (long long)bg * CHUNKS * 3;
    for (int c = 0; c < chunk; ++c) { c1 += pb[c * 3]; c2 += pb[c * 3 + 1]; ccnt += pb[c * 3 + 2]; }

    double c0    = (double)prev_count[b];
    double mean0 = (double)prev_mean[bg];
    double M2_0  = (double)prev_var[bg] * fmax(c0, 1.0);
    const float c0f = (float)c0, mean0f = (float)mean0, M2_0f = (float)M2_0;

    double run1 = c1 + ex1, run2 = c2 + ex2, runc = ccnt + (double)exc;
    #pragma unroll
    for (int e = 0; e < 2; ++e) {
        float vv = e ? v1 : v0;
        int qq = e ? q1 : q0;
        if (qq) { run1 += vv; run2 += (double)vv * vv; runc += 1.0; }
        float run1f = (float)run1, run2f = (float)run2, cv = (float)runc;
        float ctot = c0f + cv, csafe = fmaxf(ctot, 1.0f);
        float invcs = __builtin_amdgcn_rcpf(csafe);
        float meanT = fmaf(c0f, mean0f, run1f) * invcs;
        float M2 = M2_0f;
        if (runc > 0.0) {
            float invcv = __builtin_amdgcn_rcpf(cv);
            M2 += run2f - run1f * run1f * invcv;
            float dd = run1f * invcv - mean0f;
            M2 += dd * dd * c0f * cv * invcs;
        }
        float varT = M2 * invcs;
        smean[tid * 2 + e] = meanT;
        srstd[tid * 2 + e] = __builtin_amdgcn_rsqf(varT + EPSc);
    }

    if (chunk == CHUNKS - 1 && tid == 255) {
        double S1 = c1 + s1[255], S2 = c2 + s2[255], cv = ccnt + (double)sc[255];
        double ctot = c0 + cv, csafe = fmax(ctot, 1.0);
        double meanF = (c0 * mean0 + S1) / csafe;
        double M2 = M2_0;
        if (cv > 0.0) {
            M2 += S2 - S1 * S1 / cv;
            double dd = S1 / cv - mean0;
            M2 += dd * dd * c0 * cv / csafe;
        }
        double varF = M2 / csafe;
        if (g == 0) out_count[b] = (float)ctot;
        out_mean[bg] = (float)meanF;
        out_var[bg]  = (float)varF;
    }
    __syncthreads();

    const long long xbase = ((long long)b * Lc + (long long)chunk * CT2) * Dc + (long long)g * GSc;
    float4 wv = *reinterpret_cast<const float4*>(w + g * GSc + col4 * 4);
    float4 bvv = *reinterpret_cast<const float4*>(bias + g * GSc + col4 * 4);
    for (int it = 0; it < CT2 / 16; ++it) {
        int r = it * 16 + rowi;
        float mean = smean[r];
        float rstd = srstd[r];
        const float4 xv = *reinterpret_cast<const float4*>(x + xbase + (long long)r * Dc + col4 * 4);
        vfloat4 yv;
        yv.x = (xv.x - mean) * rstd * wv.x + bvv.x;
        yv.y = (xv.y - mean) * rstd * wv.y + bvv.y;
        yv.z = (xv.z - mean) * rstd * wv.z + bvv.z;
        yv.w = (xv.w - mean) * rstd * wv.w + bvv.w;
        __builtin_nontemporal_store(
            yv, reinterpret_cast<vfloat4*>(y + xbase + (long long)r * Dc + col4 * 4));
    }
}

// ================================ HOST ======================================
extern "C" void kernel_launch(void* const* d_in, const int* in_sizes, int n_in,
                              void* d_out, int out_size, void* d_ws, size_t ws_size,
                              hipStream_t stream) {
    const float* x         = (const float*)d_in[0];
    const int* prev_count  = (const int*)d_in[1];
    const float* prev_mean = (const float*)d_in[2];
    const float* prev_var  = (const float*)d_in[3];
    const int* mask        = (const int*)d_in[4];   // bool -> int32 per harness
    const float* weight    = (const float*)d_in[5];
    const float* bias      = (const float*)d_in[6];

    float* out       = (float*)d_out;
    float* y         = out;
    float* out_count = out + NY;
    float* out_mean  = out_count + Bc;
    float* out_var   = out_mean + (long long)Bc * Gc;

    double* partC = (double*)d_ws;                                   // 24 KB (coop)
    float* gmeans = (float*)((char*)d_ws + 32768);                   // 2 MB (fallback)
    double* partF = (double*)((char*)d_ws + 32768 + NM * sizeof(float));

    // Capture-safe pure query: is the coop grid co-residency satisfiable?
    int blocksPerCU = 0;
    (void)hipOccupancyMaxActiveBlocksPerMultiprocessor(&blocksPerCU, kCoop, 256, 0);
    const int coopGrid = Bc * Gc * JBc;                              // 512
    bool useCoop = ((long long)blocksPerCU * 256 >= coopGrid);

    if (useCoop) {
        void* args[] = {
            (void*)&x, (void*)&prev_count, (void*)&prev_mean, (void*)&prev_var,
            (void*)&mask, (void*)&weight, (void*)&bias, (void*)&y,
            (void*)&out_count, (void*)&out_mean, (void*)&out_var, (void*)&partC
        };
        hipError_t e = hipLaunchCooperativeKernel((void*)kCoop, dim3(coopGrid), dim3(256),
                                                  args, 0, stream);
        if (e == hipSuccess) return;
    }
    // Fallback: known-good two-kernel path (R5)
    kA<<<Bc * Gc * CHUNKS, 256, 0, stream>>>(x, mask, gmeans, partF);
    kB<<<Bc * Gc * CHUNKS, 256, 0, stream>>>(x, gmeans, partF, prev_count, prev_mean,
                                             prev_var, mask, weight, bias, y,
                                             out_count, out_mean, out_var);
}

// Round 10
// 69.653 us; speedup vs baseline: 3.2254x; 3.2254x over previous
//
#include <hip/hip_runtime.h>

namespace {
constexpr int Bc  = 4;
constexpr int Lc  = 4096;
constexpr int Dc  = 2048;
constexpr int Gc  = 32;
constexpr int GSc = 64;
constexpr int CH  = 16;                  // chunks per bg column
constexpr int CT  = Lc / CH;             // 256 timesteps per chunk
constexpr float EPSc = 1e-5f;
constexpr long long NY = (long long)Bc * Lc * Dc;   // 33,554,432
constexpr long long NM = (long long)Bc * Gc * Lc;   // 524,288
typedef float vfloat4 __attribute__((ext_vector_type(4)));
}

// kA: block = (bg, chunk). Reads its 256x64 x-slice, computes the 256 group
// means -> gmeans, and the chunk's masked fp64 (S1, S2, count) totals -> part.
// Totals accumulate in registers (segment-lane0), tiny LDS reduce at the end.
__global__ __launch_bounds__(256) void kA(const float* __restrict__ x,
                                          const int* __restrict__ mask,
                                          float* __restrict__ gmeans,
                                          double* __restrict__ part) {
    const int blk = blockIdx.x, chunk = blk & (CH - 1), bg = blk >> 4;
    const int b = bg >> 5, g = bg & (Gc - 1);
    const int tid = threadIdx.x, rseg = tid >> 4, col4 = tid & 15;
    const long long xbase = ((long long)b * Lc + (long long)chunk * CT) * Dc
                            + (long long)g * GSc + col4 * 4;
    const int* mrow = mask + (long long)b * Lc + chunk * CT;
    float* grow = gmeans + (long long)bg * Lc + chunk * CT;

    double ls1 = 0.0, ls2 = 0.0; int lc = 0;
    for (int it = 0; it < CT / 16; ++it) {       // 16 rows of 16 segments
        const int r = it * 16 + rseg;
        const float4 xv = *reinterpret_cast<const float4*>(x + xbase + (long long)r * Dc);
        float s = xv.x + xv.y + xv.z + xv.w;
        s += __shfl_xor(s, 1);
        s += __shfl_xor(s, 2);
        s += __shfl_xor(s, 4);
        s += __shfl_xor(s, 8);
        s *= (1.0f / GSc);
        if (col4 == 0) {
            grow[r] = s;
            if (mrow[r]) { ls1 += s; ls2 += (double)s * s; ++lc; }
        }
    }
    __shared__ double a1[16], a2[16];
    __shared__ int    ac[16];
    if (col4 == 0) { a1[rseg] = ls1; a2[rseg] = ls2; ac[rseg] = lc; }
    __syncthreads();
    if (tid == 0) {
        double t1 = 0.0, t2 = 0.0; int tc = 0;
        for (int i = 0; i < 16; ++i) { t1 += a1[i]; t2 += a2[i]; tc += ac[i]; }
        double* p = part + (long long)(bg * CH + chunk) * 3;
        p[0] = t1; p[1] = t2; p[2] = (double)tc;
    }
}

// kB: block = (bg, chunk), 1 timestep per thread. Wave-level fp64 shfl_up
// scan (6 steps, 1 barrier to combine 4 wave totals), one-wave carry gather,
// fp32 rcp/rsq finalize, then normalize (x re-read) with NT y-stores.
__global__ __launch_bounds__(256) void kB(const float* __restrict__ x,
                                          const float* __restrict__ gmeans,
                                          const double* __restrict__ part,
                                          const int* __restrict__ prev_count,
                                          const float* __restrict__ prev_mean,
                                          const float* __restrict__ prev_var,
                                          const int* __restrict__ mask,
                                          const float* __restrict__ w,
                                          const float* __restrict__ bias,
                                          float* __restrict__ y,
                                          float* __restrict__ out_count,
                                          float* __restrict__ out_mean,
                                          float* __restrict__ out_var) {
    const int blk = blockIdx.x, chunk = blk & (CH - 1), bg = blk >> 4;
    const int b = bg >> 5, g = bg & (Gc - 1);
    const int tid = threadIdx.x;

    __shared__ float  smean[CT], srstd[CT];
    __shared__ double wt1[4], wt2[4];
    __shared__ int    wtc[4];
    __shared__ double cLDS[3];

    // ---- per-timestep masked value ----
    const float v = gmeans[(long long)bg * Lc + chunk * CT + tid];
    const int   q = mask[(long long)b * Lc + chunk * CT + tid];
    const double l1 = q ? (double)v : 0.0;
    const double l2 = q ? (double)v * v : 0.0;
    const int    lcnt = q ? 1 : 0;

    // ---- in-wave inclusive scan (fp64 x2 + int), 6 shfl_up steps ----
    const int lane = tid & 63, wvi = tid >> 6;
    double i1 = l1, i2 = l2; int ic = lcnt;
    #pragma unroll
    for (int off = 1; off < 64; off <<= 1) {
        double t1 = __shfl_up(i1, off);
        double t2 = __shfl_up(i2, off);
        int    tc = __shfl_up(ic, off);
        if (lane >= off) { i1 += t1; i2 += t2; ic += tc; }
    }
    if (lane == 63) { wt1[wvi] = i1; wt2[wvi] = i2; wtc[wvi] = ic; }
    __syncthreads();

    // ---- carry from earlier chunks: one 16-lane gather + butterfly ----
    if (tid < 16) {
        double a1 = 0.0, a2 = 0.0, acnt = 0.0;
        if (tid < chunk) {
            const double* p = part + (long long)(bg * CH + tid) * 3;
            a1 = p[0]; a2 = p[1]; acnt = p[2];
        }
        #pragma unroll
        for (int o = 1; o < 16; o <<= 1) {
            a1 += __shfl_xor(a1, o);
            a2 += __shfl_xor(a2, o);
            acnt += __shfl_xor(acnt, o);
        }
        if (tid == 0) { cLDS[0] = a1; cLDS[1] = a2; cLDS[2] = acnt; }
    }
    __syncthreads();

    // ---- combine: carry + prior-wave totals + in-wave inclusive ----
    double o1 = cLDS[0], o2 = cLDS[1], oc = cLDS[2];
    #pragma unroll
    for (int w2 = 0; w2 < 3; ++w2) {
        if (w2 < wvi) { o1 += wt1[w2]; o2 += wt2[w2]; oc += (double)wtc[w2]; }
    }
    const double run1 = o1 + i1, run2 = o2 + i2, runc = oc + (double)ic;

    // ---- fp32 finalize (rcp/rsq; error ~1e-7 vs threshold 81.92) ----
    const double c0    = (double)prev_count[b];
    const double mean0 = (double)prev_mean[bg];
    const double M2_0  = (double)prev_var[bg] * fmax(c0, 1.0);
    const float c0f = (float)c0, mean0f = (float)mean0, M2_0f = (float)M2_0;
    {
        float run1f = (float)run1, run2f = (float)run2, cv = (float)runc;
        float ctot = c0f + cv, csafe = fmaxf(ctot, 1.0f);
        float invcs = __builtin_amdgcn_rcpf(csafe);
        float meanT = fmaf(c0f, mean0f, run1f) * invcs;
        float M2 = M2_0f;
        if (runc > 0.0) {
            float invcv = __builtin_amdgcn_rcpf(cv);
            M2 += run2f - run1f * run1f * invcv;            // batch M2
            float dd = run1f * invcv - mean0f;
            M2 += dd * dd * c0f * cv * invcs;               // Chan merge
        }
        smean[tid] = meanT;
        srstd[tid] = __builtin_amdgcn_rsqf(M2 * invcs + EPSc);
    }

    // ---- final-state outputs (fp64) from the global last timestep ----
    if (chunk == CH - 1 && tid == CT - 1) {
        double ctot = c0 + runc, csafe = fmax(ctot, 1.0);
        double meanF = (c0 * mean0 + run1) / csafe;
        double M2 = M2_0;
        if (runc > 0.0) {
            M2 += run2 - run1 * run1 / runc;
            double dd = run1 / runc - mean0;
            M2 += dd * dd * c0 * runc / csafe;
        }
        if (g == 0) out_count[b] = (float)ctot;   // buffer read back as float32
        out_mean[bg] = (float)meanF;
        out_var[bg]  = (float)(M2 / csafe);
    }
    __syncthreads();

    // ---- normalize: re-read x, NT-store y ----
    const int rseg = tid >> 4, col4 = tid & 15;
    const long long xbase = ((long long)b * Lc + (long long)chunk * CT) * Dc
                            + (long long)g * GSc + col4 * 4;
    const float4 wv4 = *reinterpret_cast<const float4*>(w + g * GSc + col4 * 4);
    const float4 bv4 = *reinterpret_cast<const float4*>(bias + g * GSc + col4 * 4);
    for (int it = 0; it < CT / 16; ++it) {
        const int r = it * 16 + rseg;
        const float mean = smean[r];              // 16-lane broadcast
        const float rstd = srstd[r];
        const float4 xv = *reinterpret_cast<const float4*>(x + xbase + (long long)r * Dc);
        vfloat4 yv;
        yv.x = (xv.x - mean) * rstd * wv4.x + bv4.x;
        yv.y = (xv.y - mean) * rstd * wv4.y + bv4.y;
        yv.z = (xv.z - mean) * rstd * wv4.z + bv4.z;
        yv.w = (xv.w - mean) * rstd * wv4.w + bv4.w;
        __builtin_nontemporal_store(
            yv, reinterpret_cast<vfloat4*>(y + xbase + (long long)r * Dc));
    }
}

extern "C" void kernel_launch(void* const* d_in, const int* in_sizes, int n_in,
                              void* d_out, int out_size, void* d_ws, size_t ws_size,
                              hipStream_t stream) {
    const float* x         = (const float*)d_in[0];
    const int* prev_count  = (const int*)d_in[1];
    const float* prev_mean = (const float*)d_in[2];
    const float* prev_var  = (const float*)d_in[3];
    const int* mask        = (const int*)d_in[4];   // bool -> int32 per harness
    const float* weight    = (const float*)d_in[5];
    const float* bias      = (const float*)d_in[6];

    float* out       = (float*)d_out;
    float* y         = out;
    float* out_count = out + NY;
    float* out_mean  = out_count + Bc;
    float* out_var   = out_mean + (long long)Bc * Gc;

    float* gmeans = (float*)d_ws;                                  // 2 MB
    double* part  = (double*)((char*)d_ws + NM * sizeof(float));   // 48 KB

    const int grid = Bc * Gc * CH;                                 // 2048 blocks
    kA<<<grid, 256, 0, stream>>>(x, mask, gmeans, part);
    kB<<<grid, 256, 0, stream>>>(x, gmeans, part, prev_count, prev_mean, prev_var,
                                 mask, weight, bias, y, out_count, out_mean, out_var);
}

// Round 11
// 65.073 us; speedup vs baseline: 3.4525x; 1.0704x over previous
//
#include <hip/hip_runtime.h>

namespace {
constexpr int Bc  = 4;
constexpr int Lc  = 4096;
constexpr int Dc  = 2048;
constexpr int Gc  = 32;
constexpr int GSc = 64;
constexpr int CH  = 8;                   // chunks per bg column
constexpr int CT  = Lc / CH;             // 512 timesteps per chunk
constexpr float EPSc = 1e-5f;
constexpr long long NY = (long long)Bc * Lc * Dc;   // 33,554,432
constexpr long long NM = (long long)Bc * Gc * Lc;   // 524,288
typedef float vfloat4 __attribute__((ext_vector_type(4)));
}

// kA: block = (bg, chunk). Reads its 512x64 x-slice, computes 512 group means
// (LDS-staged, coalesced float4 store to gmeans) and the chunk's masked fp64
// (S1, S2, count) totals -> part.  [R5's proven kA]
__global__ __launch_bounds__(256) void kA(const float* __restrict__ x,
                                          const int* __restrict__ mask,
                                          float* __restrict__ gmeans,
                                          double* __restrict__ part) {
    const int blk = blockIdx.x, chunk = blk & (CH - 1), bg = blk >> 3;
    const int b = bg >> 5, g = bg & (Gc - 1);
    const int tid = threadIdx.x, rowi = tid >> 4, col4 = tid & 15;
    const long long xbase = ((long long)b * Lc + (long long)chunk * CT) * Dc
                            + (long long)g * GSc;

    __shared__ float sm[CT];
    for (int it = 0; it < CT / 16; ++it) {       // 32 iters of 16 rows
        const int r = it * 16 + rowi;
        const float4 xv = *reinterpret_cast<const float4*>(x + xbase + (long long)r * Dc + col4 * 4);
        float s = xv.x + xv.y + xv.z + xv.w;
        s += __shfl_xor(s, 1);
        s += __shfl_xor(s, 2);
        s += __shfl_xor(s, 4);
        s += __shfl_xor(s, 8);
        if (col4 == 0) sm[r] = s * (1.0f / GSc);
    }
    __syncthreads();

    // coalesced gmeans store (128 threads x float4 = 512 floats)
    if (tid < CT / 4) {
        float4 mv = *reinterpret_cast<float4*>(sm + tid * 4);
        *reinterpret_cast<float4*>(gmeans + (long long)bg * Lc + chunk * CT + tid * 4) = mv;
    }

    // masked fp64 chunk totals: 2 elems/thread + LDS tree reduce
    const int* mrow = mask + (long long)b * Lc + chunk * CT;
    const float v0 = sm[tid * 2], v1 = sm[tid * 2 + 1];
    const int q0 = mrow[tid * 2], q1 = mrow[tid * 2 + 1];
    double ls1 = 0.0, ls2 = 0.0; int lc = 0;
    if (q0) { ls1 += v0; ls2 += (double)v0 * v0; ++lc; }
    if (q1) { ls1 += v1; ls2 += (double)v1 * v1; ++lc; }
    __shared__ double r1[256], r2[256];
    __shared__ int rc[256];
    r1[tid] = ls1; r2[tid] = ls2; rc[tid] = lc;
    __syncthreads();
    for (int off = 128; off > 0; off >>= 1) {
        if (tid < off) { r1[tid] += r1[tid + off]; r2[tid] += r2[tid + off]; rc[tid] += rc[tid + off]; }
        __syncthreads();
    }
    if (tid == 0) {
        double* p = part + (long long)(bg * CH + chunk) * 3;
        p[0] = r1[0]; p[1] = r2[0]; p[2] = (double)rc[0];
    }
}

// kB: block = (bg, chunk) via REVERSED, XCD-matched remap (reuse kA's
// still-cached tail tiles). Wave shfl_up scan (2 elems/thread), 8-lane carry
// butterfly, fp32 rcp/rsq finalize, normalize (x re-read) with NT y-stores.
__global__ __launch_bounds__(256) void kB(const float* __restrict__ x,
                                          const float* __restrict__ gmeans,
                                          const double* __restrict__ part,
                                          const int* __restrict__ prev_count,
                                          const float* __restrict__ prev_mean,
                                          const float* __restrict__ prev_var,
                                          const int* __restrict__ mask,
                                          const float* __restrict__ w,
                                          const float* __restrict__ bias,
                                          float* __restrict__ y,
                                          float* __restrict__ out_count,
                                          float* __restrict__ out_mean,
                                          float* __restrict__ out_var) {
    // reverse order, same XCD class (blk2 % 8 == blockIdx.x % 8)
    const int i = blockIdx.x;
    const int blk2 = (Bc * Gc * CH - 8 - (i & ~7)) + (i & 7);
    const int chunk = blk2 & (CH - 1), bg = blk2 >> 3;
    const int b = bg >> 5, g = bg & (Gc - 1);
    const int tid = threadIdx.x;
    const int lane = tid & 63, wvi = tid >> 6;

    __shared__ float  smean[CT], srstd[CT];
    __shared__ double wt1[4], wt2[4];
    __shared__ int    wtc[4];
    __shared__ double cLDS[3];

    // ---- per-thread pair of timesteps ----
    const float2 vv = *reinterpret_cast<const float2*>(gmeans + (long long)bg * Lc + chunk * CT + 2 * tid);
    const int2   qq = *reinterpret_cast<const int2*>(mask + (long long)b * Lc + chunk * CT + 2 * tid);
    const double e10 = qq.x ? (double)vv.x : 0.0;
    const double e20 = qq.x ? (double)vv.x * vv.x : 0.0;
    const double e11 = qq.y ? (double)vv.y : 0.0;
    const double e21 = qq.y ? (double)vv.y * vv.y : 0.0;
    const int    ec  = (qq.x ? 1 : 0) + (qq.y ? 1 : 0);
    const double P1 = e10 + e11, P2 = e20 + e21;

    // ---- in-wave inclusive scan over pair-sums (6 shfl_up steps) ----
    double i1 = P1, i2 = P2; int ic = ec;
    #pragma unroll
    for (int off = 1; off < 64; off <<= 1) {
        double t1 = __shfl_up(i1, off);
        double t2 = __shfl_up(i2, off);
        int    tc = __shfl_up(ic, off);
        if (lane >= off) { i1 += t1; i2 += t2; ic += tc; }
    }
    if (lane == 63) { wt1[wvi] = i1; wt2[wvi] = i2; wtc[wvi] = ic; }

    // ---- carry from earlier chunks: 8-lane gather + butterfly ----
    if (tid < 8) {
        double a1 = 0.0, a2 = 0.0, acnt = 0.0;
        if (tid < chunk) {
            const double* p = part + (long long)(bg * CH + tid) * 3;
            a1 = p[0]; a2 = p[1]; acnt = p[2];
        }
        #pragma unroll
        for (int o = 1; o < 8; o <<= 1) {
            a1 += __shfl_xor(a1, o);
            a2 += __shfl_xor(a2, o);
            acnt += __shfl_xor(acnt, o);
        }
        if (tid == 0) { cLDS[0] = a1; cLDS[1] = a2; cLDS[2] = acnt; }
    }
    __syncthreads();

    // ---- combine: carry + prior-wave totals + in-wave exclusive ----
    double o1 = cLDS[0], o2 = cLDS[1], oc = cLDS[2];
    #pragma unroll
    for (int w2 = 0; w2 < 3; ++w2) {
        if (w2 < wvi) { o1 += wt1[w2]; o2 += wt2[w2]; oc += (double)wtc[w2]; }
    }
    double run1 = o1 + (i1 - P1), run2 = o2 + (i2 - P2), runc = oc + (double)(ic - ec);

    // ---- fp32 finalize (rcp/rsq) for the 2 timesteps ----
    const double c0    = (double)prev_count[b];
    const double mean0 = (double)prev_mean[bg];
    const double M2_0  = (double)prev_var[bg] * fmax(c0, 1.0);
    const float c0f = (float)c0, mean0f = (float)mean0, M2_0f = (float)M2_0;
    #pragma unroll
    for (int e = 0; e < 2; ++e) {
        run1 += e ? e11 : e10;
        run2 += e ? e21 : e20;
        runc += (e ? (qq.y ? 1.0 : 0.0) : (qq.x ? 1.0 : 0.0));
        float run1f = (float)run1, run2f = (float)run2, cv = (float)runc;
        float ctot = c0f + cv, csafe = fmaxf(ctot, 1.0f);
        float invcs = __builtin_amdgcn_rcpf(csafe);
        float meanT = fmaf(c0f, mean0f, run1f) * invcs;
        float M2 = M2_0f;
        if (runc > 0.0) {
            float invcv = __builtin_amdgcn_rcpf(cv);
            M2 += run2f - run1f * run1f * invcv;            // batch M2
            float dd = run1f * invcv - mean0f;
            M2 += dd * dd * c0f * cv * invcs;               // Chan merge
        }
        smean[2 * tid + e] = meanT;
        srstd[2 * tid + e] = __builtin_amdgcn_rsqf(M2 * invcs + EPSc);
    }

    // ---- final-state outputs (fp64) from the global last timestep ----
    if (chunk == CH - 1 && tid == 255) {
        double ctot = c0 + runc, csafe = fmax(ctot, 1.0);
        double meanF = (c0 * mean0 + run1) / csafe;
        double M2 = M2_0;
        if (runc > 0.0) {
            M2 += run2 - run1 * run1 / runc;
            double dd = run1 / runc - mean0;
            M2 += dd * dd * c0 * runc / csafe;
        }
        if (g == 0) out_count[b] = (float)ctot;   // buffer read back as float32
        out_mean[bg] = (float)meanF;
        out_var[bg]  = (float)(M2 / csafe);
    }
    __syncthreads();

    // ---- normalize: re-read x, NT-store y ----
    const int rseg = tid >> 4, col4 = tid & 15;
    const long long xbase = ((long long)b * Lc + (long long)chunk * CT) * Dc
                            + (long long)g * GSc + col4 * 4;
    const float4 wv4 = *reinterpret_cast<const float4*>(w + g * GSc + col4 * 4);
    const float4 bv4 = *reinterpret_cast<const float4*>(bias + g * GSc + col4 * 4);
    for (int it = 0; it < CT / 16; ++it) {
        const int r = it * 16 + rseg;
        const float mean = smean[r];              // 16-lane broadcast
        const float rstd = srstd[r];
        const float4 xv = *reinterpret_cast<const float4*>(x + xbase + (long long)r * Dc);
        vfloat4 yv;
        yv.x = (xv.x - mean) * rstd * wv4.x + bv4.x;
        yv.y = (xv.y - mean) * rstd * wv4.y + bv4.y;
        yv.z = (xv.z - mean) * rstd * wv4.z + bv4.z;
        yv.w = (xv.w - mean) * rstd * wv4.w + bv4.w;
        __builtin_nontemporal_store(
            yv, reinterpret_cast<vfloat4*>(y + xbase + (long long)r * Dc));
    }
}

extern "C" void kernel_launch(void* const* d_in, const int* in_sizes, int n_in,
                              void* d_out, int out_size, void* d_ws, size_t ws_size,
                              hipStream_t stream) {
    const float* x         = (const float*)d_in[0];
    const int* prev_count  = (const int*)d_in[1];
    const float* prev_mean = (const float*)d_in[2];
    const float* prev_var  = (const float*)d_in[3];
    const int* mask        = (const int*)d_in[4];   // bool -> int32 per harness
    const float* weight    = (const float*)d_in[5];
    const float* bias      = (const float*)d_in[6];

    float* out       = (float*)d_out;
    float* y         = out;
    float* out_count = out + NY;
    float* out_mean  = out_count + Bc;
    float* out_var   = out_mean + (long long)Bc * Gc;

    float* gmeans = (float*)d_ws;                                  // 2 MB
    double* part  = (double*)((char*)d_ws + NM * sizeof(float));   // 24 KB

    const int grid = Bc * Gc * CH;                                 // 1024 blocks
    kA<<<grid, 256, 0, stream>>>(x, mask, gmeans, part);
    kB<<<grid, 256, 0, stream>>>(x, gmeans, part, prev_count, prev_mean, prev_var,
                                 mask, weight, bias, y, out_count, out_mean, out_var);
}